// Round 13
// baseline (143.976 us; speedup 1.0000x reference)
//
#include <hip/hip_runtime.h>
#include <hip/hip_bf16.h>
#include <math.h>

#define SA_N 2048
#define SA_D 1024
#define SA_H 16
#define SA_HD 64

typedef __attribute__((ext_vector_type(8))) short bf16x8;
typedef __attribute__((ext_vector_type(4))) float f32x4;
typedef __attribute__((address_space(3))) void lds_t;
typedef __attribute__((address_space(1))) void gmem_t;

#define SC2 0.18033688011112042f   // (1/sqrt(64)) * log2(e), folded into Wq/bq

// ---------------- merged prep: x->bf16 and 4x W[K][N] -> bf16 Wt[N][K] ----------------
__global__ __launch_bounds__(256) void prep_kernel(
    const float* __restrict__ x,
    const float* __restrict__ Wq, const float* __restrict__ Wk,
    const float* __restrict__ Wv, const float* __restrict__ Wo,
    __hip_bfloat16* __restrict__ xbf, __hip_bfloat16* __restrict__ WtAll)
{
    const int tid = threadIdx.x;
    const int z = blockIdx.z;
    if (z < 2) {
        const int r = z * 1024 + blockIdx.y * 32 + (tid >> 3);
        const int c = blockIdx.x * 32 + (tid & 7) * 4;
        const size_t idx = (size_t)r * SA_D + c;
        float4 v = *reinterpret_cast<const float4*>(&x[idx]);
        union { __hip_bfloat16 hh[4]; short4 s4; } u;
        u.hh[0] = __float2bfloat16(v.x);
        u.hh[1] = __float2bfloat16(v.y);
        u.hh[2] = __float2bfloat16(v.z);
        u.hh[3] = __float2bfloat16(v.w);
        *reinterpret_cast<short4*>(&xbf[idx]) = u.s4;
    } else {
        const int w = z - 2;
        const float* W = (w == 0) ? Wq : (w == 1) ? Wk : (w == 2) ? Wv : Wo;
        const float scale = (w == 0) ? SC2 : 1.0f;
        __hip_bfloat16* Wt = WtAll + (size_t)w * SA_D * SA_D;
        __shared__ float t[32][33];
        const int c0 = blockIdx.x * 32, r0 = blockIdx.y * 32;
        const int tx = tid & 31, ty = tid >> 5;
#pragma unroll
        for (int p = 0; p < 4; ++p)
            t[ty + p * 8][tx] = W[(size_t)(r0 + ty + p * 8) * SA_D + c0 + tx] * scale;
        __syncthreads();
#pragma unroll
        for (int p = 0; p < 4; ++p)
            Wt[(size_t)(c0 + ty + p * 8) * SA_D + r0 + tx] =
                __float2bfloat16(t[tx][ty + p * 8]);
    }
}

// ---------------- fused QKV GEMM + permuted-key V output (v7 permutation) ----------------
// V key permutation within each 64-key block: key offset K (t=K>>4, q=(K>>2)&3,
// r=K&3) -> k' = (t&1)*32 + q*8 + (t>>1)*4 + r. This matches the flash kernel's
// register-resident P^T fragments (P never touches LDS there).
__global__ __launch_bounds__(256) void gemm_qkv_kernel(
    const __hip_bfloat16* __restrict__ xbf, const __hip_bfloat16* __restrict__ WtAll,
    const float* __restrict__ bq, const float* __restrict__ bk, const float* __restrict__ bv,
    __hip_bfloat16* __restrict__ Qb, __hip_bfloat16* __restrict__ Kb,
    __hip_bfloat16* __restrict__ VtT)
{
    __shared__ __align__(16) char As[64 * 128];
    __shared__ __align__(16) char Bs[3][32 * 128];

    const int tid = threadIdx.x;
    const int wave = tid >> 6, lane = tid & 63;
    const int m = lane & 15, quad = lane >> 4;
    const int wm = wave >> 1, wn = wave & 1;
    const int row0 = blockIdx.y * 64, col0 = blockIdx.x * 32;

    f32x4 acc[3][2];
#pragma unroll
    for (int w = 0; w < 3; ++w)
#pragma unroll
        for (int mi = 0; mi < 2; ++mi) acc[w][mi] = (f32x4){0.f, 0.f, 0.f, 0.f};

    const int sr = tid >> 3;   // 0..31
    const int sc = tid & 7;    // chunk

    for (int k0 = 0; k0 < SA_D; k0 += 64) {
#pragma unroll
        for (int p = 0; p < 2; ++p) {
            const int r = p * 32 + sr;
            const int pc = (sc ^ (r & 7)) * 16;
            const char* ga = (const char*)(xbf + (size_t)(row0 + r) * SA_D + k0) + pc;
            __builtin_amdgcn_global_load_lds((gmem_t*)ga,
                (lds_t*)(As + p * 4096 + wave * 1024), 16, 0, 0);
        }
#pragma unroll
        for (int w = 0; w < 3; ++w) {
            const int pc = (sc ^ (sr & 7)) * 16;
            const char* gb = (const char*)(WtAll + (size_t)w * SA_D * SA_D
                                           + (size_t)(col0 + sr) * SA_D + k0) + pc;
            __builtin_amdgcn_global_load_lds((gmem_t*)gb,
                (lds_t*)(Bs[w] + wave * 1024), 16, 0, 0);
        }
        __syncthreads();

#pragma unroll
        for (int s = 0; s < 2; ++s) {
            bf16x8 af[2];
#pragma unroll
            for (int mi = 0; mi < 2; ++mi) {
                const int row = wm * 32 + mi * 16 + m;
                const int pc = (s * 4 + quad) ^ (row & 7);
                af[mi] = *reinterpret_cast<const bf16x8*>(As + row * 128 + pc * 16);
            }
            const int rb = wn * 16 + m;
            const int pcb = (s * 4 + quad) ^ (rb & 7);
#pragma unroll
            for (int w = 0; w < 3; ++w) {
                bf16x8 bf = *reinterpret_cast<const bf16x8*>(Bs[w] + rb * 128 + pcb * 16);
#pragma unroll
                for (int mi = 0; mi < 2; ++mi)
                    acc[w][mi] = __builtin_amdgcn_mfma_f32_16x16x32_bf16(
                        af[mi], bf, acc[w][mi], 0, 0, 0);
            }
        }
        __syncthreads();
    }

    // epilogue: Q,K natural bf16; V transposed [N][M] bf16 with v7 key permutation
    const int col = col0 + wn * 16 + m;
    const float bvq = bq[col] * SC2, bvk = bk[col], bvv = bv[col];
#pragma unroll
    for (int mi = 0; mi < 2; ++mi) {
        const int rbase = row0 + wm * 32 + mi * 16 + quad * 4;
#pragma unroll
        for (int reg = 0; reg < 4; ++reg) {
            Qb[(size_t)(rbase + reg) * SA_D + col] = __float2bfloat16(acc[0][mi][reg] + bvq);
            Kb[(size_t)(rbase + reg) * SA_D + col] = __float2bfloat16(acc[1][mi][reg] + bvk);
        }
        // K_off = wm*32+mi*16+quad*4+reg -> k' = mi*32 + quad*8 + wm*4 + reg (contiguous!)
        union { __hip_bfloat16 hh[4]; short4 s4; } u;
#pragma unroll
        for (int reg = 0; reg < 4; ++reg)
            u.hh[reg] = __float2bfloat16(acc[2][mi][reg] + bvv);
        *reinterpret_cast<short4*>(
            &VtT[(size_t)col * SA_N + row0 + mi * 32 + quad * 8 + wm * 4]) = u.s4;
    }
}

// ---------------- bf16 MFMA GEMM 64x64 (out-proj, unchanged) ----------------
__global__ __launch_bounds__(256) void gemm_out_kernel(
    const __hip_bfloat16* __restrict__ A, const __hip_bfloat16* __restrict__ Bt,
    const float* __restrict__ bias, float* __restrict__ Cout)
{
    __shared__ __align__(16) char As[64 * 128];
    __shared__ __align__(16) char Bs[64 * 128];
    const int tid = threadIdx.x;
    const int wave = tid >> 6, lane = tid & 63;
    const int m = lane & 15, quad = lane >> 4;
    const int wm = wave >> 1, wn = wave & 1;
    const int row0 = blockIdx.y * 64, col0 = blockIdx.x * 64;

    f32x4 acc[2][2];
#pragma unroll
    for (int i = 0; i < 2; ++i)
#pragma unroll
        for (int j = 0; j < 2; ++j) acc[i][j] = (f32x4){0.f, 0.f, 0.f, 0.f};

    const int sr = tid >> 3;
    const int sc = tid & 7;

    for (int k0 = 0; k0 < SA_D; k0 += 64) {
#pragma unroll
        for (int p = 0; p < 2; ++p) {
            const int r = p * 32 + sr;
            const int pc = (sc ^ (r & 7)) * 16;
            const char* ga = (const char*)(A + (size_t)(row0 + r) * SA_D + k0) + pc;
            __builtin_amdgcn_global_load_lds((gmem_t*)ga,
                (lds_t*)(As + p * 4096 + wave * 1024), 16, 0, 0);
            const char* gb = (const char*)(Bt + (size_t)(col0 + r) * SA_D + k0) + pc;
            __builtin_amdgcn_global_load_lds((gmem_t*)gb,
                (lds_t*)(Bs + p * 4096 + wave * 1024), 16, 0, 0);
        }
        __syncthreads();

#pragma unroll
        for (int s = 0; s < 2; ++s) {
            bf16x8 af[2], bfr[2];
#pragma unroll
            for (int mi = 0; mi < 2; ++mi) {
                const int row = wm * 32 + mi * 16 + m;
                const int pc = (s * 4 + quad) ^ (row & 7);
                af[mi] = *reinterpret_cast<const bf16x8*>(As + row * 128 + pc * 16);
            }
#pragma unroll
            for (int ni = 0; ni < 2; ++ni) {
                const int col = wn * 32 + ni * 16 + m;
                const int pc = (s * 4 + quad) ^ (col & 7);
                bfr[ni] = *reinterpret_cast<const bf16x8*>(Bs + col * 128 + pc * 16);
            }
#pragma unroll
            for (int mi = 0; mi < 2; ++mi)
#pragma unroll
                for (int ni = 0; ni < 2; ++ni)
                    acc[mi][ni] = __builtin_amdgcn_mfma_f32_16x16x32_bf16(
                        af[mi], bfr[ni], acc[mi][ni], 0, 0, 0);
        }
        __syncthreads();
    }

#pragma unroll
    for (int ni = 0; ni < 2; ++ni) {
        const int col = col0 + wn * 32 + ni * 16 + m;
        const float bv = bias[col];
#pragma unroll
        for (int mi = 0; mi < 2; ++mi) {
            const int rbase = row0 + wm * 32 + mi * 16 + quad * 4;
#pragma unroll
            for (int reg = 0; reg < 4; ++reg)
                Cout[(size_t)(rbase + reg) * SA_D + col] = acc[mi][ni][reg] + bv;
        }
    }
}

// ---------------- MFMA flash attention v7: S^T trick, P stays in registers ----------------
// Compute S^T = K·Q^T (A=K-rows from LDS, B=Q-rows from registers). Lane (ln,quad)
// tile gg reg r then holds P[qrow=ln][key = gg*16+quad*4+r] — its OWN query row.
// With V keys permuted as k' = (t&1)*32 + quad*8 + (t>>1)*4 + r, the PV A-fragments
// assemble directly from sacc registers: pf[0]=cvt(sacc[0]||sacc[2]),
// pf[1]=cvt(sacc[1]||sacc[3]). No P LDS round-trip; no Qs; l accumulated as fp32
// scalar per lane (quad-reduced once at the end).
// LDS: Ks 16K + Vs 16K + lm 512B = 32.5 KB. launch_bounds(512,6) -> 3 blocks/CU.
__global__ __launch_bounds__(512, 6) void flash_mfma_kernel(
    const __hip_bfloat16* __restrict__ Qb,  // [N][D], pre-scaled by SC2
    const __hip_bfloat16* __restrict__ Kb,  // [N][D]
    const __hip_bfloat16* __restrict__ Vt,  // [D][N], keys permuted per 64-block
    __hip_bfloat16* __restrict__ O)         // [N][D]
{
    const int b = blockIdx.x;
    const int h = b & 15;
    const int qraw = b >> 4;
    const int qt = (qraw < 16) ? qraw : 47 - qraw;  // fold for CU balance
    const int row0 = qt * 64;
    const int ntiles = (qt >> 1) + 1;               // 128-key tiles

    const int tid = threadIdx.x;
    const int wave = tid >> 6, lane = tid & 63;
    const int g = wave >> 2, w4 = wave & 3;         // group, wave-in-group
    const int ln = lane & 15, quad = lane >> 4;

    __shared__ __align__(16) char Ks[128 * 128];    // [key][dim] bf16 (reused as merge buf)
    __shared__ __align__(16) char Vs[64 * 256];     // [dim][k'] bf16, 128 keys/row
    __shared__ float lm[2][64];

    // Q B-fragments in registers (one-time, L2-hot; same fragment as verified R9)
    bf16x8 qf[2];
#pragma unroll
    for (int s = 0; s < 2; ++s)
        qf[s] = *reinterpret_cast<const bf16x8*>(
            Qb + (size_t)(row0 + w4 * 16 + ln) * SA_D + h * SA_HD + s * 32 + quad * 8);

    f32x4 oacc[4];
#pragma unroll
    for (int dg = 0; dg < 4; ++dg) oacc[dg] = (f32x4){0.f, 0.f, 0.f, 0.f};
    float lsum = 0.f;   // partial row-sum for qrow = w4*16+ln over this quad's keys

    for (int kt = 0; kt < ntiles; ++kt) {
        __syncthreads();
#pragma unroll
        for (int p = 0; p < 2; ++p) {
            const int r = p * 64 + wave * 8 + (lane >> 3);
            const int pc = ((lane & 7) ^ (r & 7)) * 16;
            const char* gk = (const char*)(Kb + (size_t)(kt * 128 + r) * SA_D + h * SA_HD) + pc;
            __builtin_amdgcn_global_load_lds((gmem_t*)gk,
                (lds_t*)(Ks + p * 8192 + wave * 1024), 16, 0, 0);
        }
#pragma unroll
        for (int p = 0; p < 2; ++p) {
            const int r = p * 32 + wave * 4 + (lane >> 4);
            const int pc = ((lane & 15) ^ (r & 15)) * 16;
            const char* gv = (const char*)(Vt + (size_t)(h * SA_HD + r) * SA_N + kt * 128) + pc;
            __builtin_amdgcn_global_load_lds((gmem_t*)gv,
                (lds_t*)(Vs + p * 8192 + wave * 1024), 16, 0, 0);
        }
        __syncthreads();

        // S^T = K Q^T : 4 tiles of 16 keys x 16 qrows
        f32x4 sacc[4];
#pragma unroll
        for (int gg = 0; gg < 4; ++gg) sacc[gg] = (f32x4){0.f, 0.f, 0.f, 0.f};
#pragma unroll
        for (int s = 0; s < 2; ++s) {
#pragma unroll
            for (int gg = 0; gg < 4; ++gg) {
                const int krow = g * 64 + gg * 16 + ln;
                const int pcb = (s * 4 + quad) ^ (krow & 7);
                bf16x8 af = *reinterpret_cast<const bf16x8*>(Ks + krow * 128 + pcb * 16);
                sacc[gg] = __builtin_amdgcn_mfma_f32_16x16x32_bf16(af, qf[s], sacc[gg], 0, 0, 0);
            }
        }

        // P = exp2(S) + causal mask, in registers; accumulate lsum
        const bool last = (kt == ntiles - 1);
        const int qrow_g = row0 + w4 * 16 + ln;
        __hip_bfloat16 ph[4][4];
#pragma unroll
        for (int gg = 0; gg < 4; ++gg) {
            const int keyb = kt * 128 + g * 64 + gg * 16 + quad * 4;
#pragma unroll
            for (int reg = 0; reg < 4; ++reg) {
                float p = exp2f(sacc[gg][reg]);
                if (last && (keyb + reg) > qrow_g) p = 0.f;
                lsum += p;
                ph[gg][reg] = __float2bfloat16(p);
            }
        }
        // pf[s2]: k' = s2*32 + quad*8 + j ; j=0..3 from tile 2*?... t even->s2=0, odd->s2=1
        bf16x8 pf[2];
        union { __hip_bfloat16 hh[8]; bf16x8 v; } pu0, pu1;
#pragma unroll
        for (int reg = 0; reg < 4; ++reg) {
            pu0.hh[reg] = ph[0][reg]; pu0.hh[4 + reg] = ph[2][reg];
            pu1.hh[reg] = ph[1][reg]; pu1.hh[4 + reg] = ph[3][reg];
        }
        pf[0] = pu0.v; pf[1] = pu1.v;

        // O += P V  (A-frag from registers, B-frag from Vs)
#pragma unroll
        for (int s2 = 0; s2 < 2; ++s2) {
#pragma unroll
            for (int dg = 0; dg < 4; ++dg) {
                const int vrow = dg * 16 + ln;
                const int kc = g * 8 + s2 * 4 + quad;
                const int pcb = (kc ^ (vrow & 15)) * 16;
                bf16x8 vf = *reinterpret_cast<const bf16x8*>(Vs + vrow * 256 + pcb);
                oacc[dg] = __builtin_amdgcn_mfma_f32_16x16x32_bf16(pf[s2], vf, oacc[dg], 0, 0, 0);
            }
        }
    }

    // l: reduce over quads (lanes ln, ln+16, ln+32, ln+48), publish per group
    lsum += __shfl_xor(lsum, 16);
    lsum += __shfl_xor(lsum, 32);
    if (quad == 0) lm[g][w4 * 16 + ln] = lsum;

    // merge groups: group 1 dumps fp32 partials into Ks (16 KB = 64x64 f32)
    __syncthreads();
    float* Kf = reinterpret_cast<float*>(Ks);
    if (g == 1) {
#pragma unroll
        for (int reg = 0; reg < 4; ++reg) {
            const int row = w4 * 16 + quad * 4 + reg;
#pragma unroll
            for (int dg = 0; dg < 4; ++dg)
                Kf[row * 64 + dg * 16 + ln] = oacc[dg][reg];
        }
    }
    __syncthreads();
    if (g == 0) {
#pragma unroll
        for (int reg = 0; reg < 4; ++reg) {
            const int row = w4 * 16 + quad * 4 + reg;
            const float inv = 1.0f / (lm[0][row] + lm[1][row]);
            const int qrow = row0 + row;
#pragma unroll
            for (int dg = 0; dg < 4; ++dg)
                O[(size_t)qrow * SA_D + h * SA_HD + dg * 16 + ln] =
                    __float2bfloat16((oacc[dg][reg] + Kf[row * 64 + dg * 16 + ln]) * inv);
        }
    }
}

extern "C" void kernel_launch(void* const* d_in, const int* in_sizes, int n_in,
                              void* d_out, int out_size, void* d_ws, size_t ws_size,
                              hipStream_t stream) {
    const float* x  = (const float*)d_in[0];
    const float* Wq = (const float*)d_in[1];
    const float* bq = (const float*)d_in[2];
    const float* Wk = (const float*)d_in[3];
    const float* bk = (const float*)d_in[4];
    const float* Wv = (const float*)d_in[5];
    const float* bv = (const float*)d_in[6];
    const float* Wo = (const float*)d_in[7];
    const float* bo = (const float*)d_in[8];
    float* out = (float*)d_out;

    const size_t ND = (size_t)SA_N * SA_D;
    const size_t DD = (size_t)SA_D * SA_D;
    __hip_bfloat16* xbf   = (__hip_bfloat16*)d_ws;
    __hip_bfloat16* WtAll = xbf + ND;
    __hip_bfloat16* Qb    = WtAll + 4 * DD;
    __hip_bfloat16* Kb    = Qb + ND;
    __hip_bfloat16* VtT   = Kb + ND;
    __hip_bfloat16* Abf   = VtT + ND;

    prep_kernel<<<dim3(32, 32, 6), 256, 0, stream>>>(x, Wq, Wk, Wv, Wo, xbf, WtAll);
    gemm_qkv_kernel<<<dim3(SA_D / 32, SA_N / 64), 256, 0, stream>>>(
        xbf, WtAll, bq, bk, bv, Qb, Kb, VtT);
    flash_mfma_kernel<<<dim3(512), 512, 0, stream>>>(Qb, Kb, VtT, Abf);
    gemm_out_kernel<<<dim3(SA_D / 64, SA_N / 64), 256, 0, stream>>>(
        Abf, WtAll + 3 * DD, bo, out);
}

// Round 14
// 141.448 us; speedup vs baseline: 1.0179x; 1.0179x over previous
//
#include <hip/hip_runtime.h>
#include <hip/hip_bf16.h>
#include <math.h>

#define SA_N 2048
#define SA_D 1024
#define SA_H 16
#define SA_HD 64

typedef __attribute__((ext_vector_type(8))) short bf16x8;
typedef __attribute__((ext_vector_type(4))) float f32x4;
typedef __attribute__((address_space(3))) void lds_t;
typedef __attribute__((address_space(1))) void gmem_t;

#define SC2 0.18033688011112042f   // (1/sqrt(64)) * log2(e), folded into Wq/bq

// ---------------- merged prep: x->bf16 and 4x W[K][N] -> bf16 Wt[N][K] ----------------
__global__ __launch_bounds__(256) void prep_kernel(
    const float* __restrict__ x,
    const float* __restrict__ Wq, const float* __restrict__ Wk,
    const float* __restrict__ Wv, const float* __restrict__ Wo,
    __hip_bfloat16* __restrict__ xbf, __hip_bfloat16* __restrict__ WtAll)
{
    const int tid = threadIdx.x;
    const int z = blockIdx.z;
    if (z < 2) {
        const int r = z * 1024 + blockIdx.y * 32 + (tid >> 3);
        const int c = blockIdx.x * 32 + (tid & 7) * 4;
        const size_t idx = (size_t)r * SA_D + c;
        float4 v = *reinterpret_cast<const float4*>(&x[idx]);
        union { __hip_bfloat16 hh[4]; short4 s4; } u;
        u.hh[0] = __float2bfloat16(v.x);
        u.hh[1] = __float2bfloat16(v.y);
        u.hh[2] = __float2bfloat16(v.z);
        u.hh[3] = __float2bfloat16(v.w);
        *reinterpret_cast<short4*>(&xbf[idx]) = u.s4;
    } else {
        const int w = z - 2;
        const float* W = (w == 0) ? Wq : (w == 1) ? Wk : (w == 2) ? Wv : Wo;
        const float scale = (w == 0) ? SC2 : 1.0f;
        __hip_bfloat16* Wt = WtAll + (size_t)w * SA_D * SA_D;
        __shared__ float t[32][33];
        const int c0 = blockIdx.x * 32, r0 = blockIdx.y * 32;
        const int tx = tid & 31, ty = tid >> 5;
#pragma unroll
        for (int p = 0; p < 4; ++p)
            t[ty + p * 8][tx] = W[(size_t)(r0 + ty + p * 8) * SA_D + c0 + tx] * scale;
        __syncthreads();
#pragma unroll
        for (int p = 0; p < 4; ++p)
            Wt[(size_t)(c0 + ty + p * 8) * SA_D + r0 + tx] =
                __float2bfloat16(t[tx][ty + p * 8]);
    }
}

// ---------------- fused QKV GEMM (exact R12) + permuted-key V output ----------------
__global__ __launch_bounds__(256) void gemm_qkv_kernel(
    const __hip_bfloat16* __restrict__ xbf, const __hip_bfloat16* __restrict__ WtAll,
    const float* __restrict__ bq, const float* __restrict__ bk, const float* __restrict__ bv,
    __hip_bfloat16* __restrict__ Qb, __hip_bfloat16* __restrict__ Kb,
    __hip_bfloat16* __restrict__ VtT)
{
    __shared__ __align__(16) char As[64 * 128];
    __shared__ __align__(16) char Bs[3][32 * 128];

    const int tid = threadIdx.x;
    const int wave = tid >> 6, lane = tid & 63;
    const int m = lane & 15, quad = lane >> 4;
    const int wm = wave >> 1, wn = wave & 1;
    const int row0 = blockIdx.y * 64, col0 = blockIdx.x * 32;

    f32x4 acc[3][2];
#pragma unroll
    for (int w = 0; w < 3; ++w)
#pragma unroll
        for (int mi = 0; mi < 2; ++mi) acc[w][mi] = (f32x4){0.f, 0.f, 0.f, 0.f};

    const int sr = tid >> 3;   // 0..31
    const int sc = tid & 7;    // chunk

    for (int k0 = 0; k0 < SA_D; k0 += 64) {
#pragma unroll
        for (int p = 0; p < 2; ++p) {
            const int r = p * 32 + sr;
            const int pc = (sc ^ (r & 7)) * 16;
            const char* ga = (const char*)(xbf + (size_t)(row0 + r) * SA_D + k0) + pc;
            __builtin_amdgcn_global_load_lds((gmem_t*)ga,
                (lds_t*)(As + p * 4096 + wave * 1024), 16, 0, 0);
        }
#pragma unroll
        for (int w = 0; w < 3; ++w) {
            const int pc = (sc ^ (sr & 7)) * 16;
            const char* gb = (const char*)(WtAll + (size_t)w * SA_D * SA_D
                                           + (size_t)(col0 + sr) * SA_D + k0) + pc;
            __builtin_amdgcn_global_load_lds((gmem_t*)gb,
                (lds_t*)(Bs[w] + wave * 1024), 16, 0, 0);
        }
        __syncthreads();

#pragma unroll
        for (int s = 0; s < 2; ++s) {
            bf16x8 af[2];
#pragma unroll
            for (int mi = 0; mi < 2; ++mi) {
                const int row = wm * 32 + mi * 16 + m;
                const int pc = (s * 4 + quad) ^ (row & 7);
                af[mi] = *reinterpret_cast<const bf16x8*>(As + row * 128 + pc * 16);
            }
            const int rb = wn * 16 + m;
            const int pcb = (s * 4 + quad) ^ (rb & 7);
#pragma unroll
            for (int w = 0; w < 3; ++w) {
                bf16x8 bf = *reinterpret_cast<const bf16x8*>(Bs[w] + rb * 128 + pcb * 16);
#pragma unroll
                for (int mi = 0; mi < 2; ++mi)
                    acc[w][mi] = __builtin_amdgcn_mfma_f32_16x16x32_bf16(
                        af[mi], bf, acc[w][mi], 0, 0, 0);
            }
        }
        __syncthreads();
    }

    // epilogue: Q,K natural bf16; V transposed [N][M] bf16 with R12 key permutation
    const int col = col0 + wn * 16 + m;
    const float bvq = bq[col] * SC2, bvk = bk[col], bvv = bv[col];
#pragma unroll
    for (int mi = 0; mi < 2; ++mi) {
        const int rbase = row0 + wm * 32 + mi * 16 + quad * 4;
#pragma unroll
        for (int reg = 0; reg < 4; ++reg) {
            Qb[(size_t)(rbase + reg) * SA_D + col] = __float2bfloat16(acc[0][mi][reg] + bvq);
            Kb[(size_t)(rbase + reg) * SA_D + col] = __float2bfloat16(acc[1][mi][reg] + bvk);
        }
        // permuted V store: key K=rbase+reg -> row0 + (quad*4+reg)*4 + (wm*2+mi)
#pragma unroll
        for (int reg = 0; reg < 4; ++reg) {
            const int jp = (quad * 4 + reg) * 4 + (wm * 2 + mi);
            VtT[(size_t)col * SA_N + row0 + jp] = __float2bfloat16(acc[2][mi][reg] + bvv);
        }
    }
}

// ---------------- bf16 MFMA GEMM 64x64 (out-proj, exact R12) ----------------
__global__ __launch_bounds__(256) void gemm_out_kernel(
    const __hip_bfloat16* __restrict__ A, const __hip_bfloat16* __restrict__ Bt,
    const float* __restrict__ bias, float* __restrict__ Cout)
{
    __shared__ __align__(16) char As[64 * 128];
    __shared__ __align__(16) char Bs[64 * 128];
    const int tid = threadIdx.x;
    const int wave = tid >> 6, lane = tid & 63;
    const int m = lane & 15, quad = lane >> 4;
    const int wm = wave >> 1, wn = wave & 1;
    const int row0 = blockIdx.y * 64, col0 = blockIdx.x * 64;

    f32x4 acc[2][2];
#pragma unroll
    for (int i = 0; i < 2; ++i)
#pragma unroll
        for (int j = 0; j < 2; ++j) acc[i][j] = (f32x4){0.f, 0.f, 0.f, 0.f};

    const int sr = tid >> 3;
    const int sc = tid & 7;

    for (int k0 = 0; k0 < SA_D; k0 += 64) {
#pragma unroll
        for (int p = 0; p < 2; ++p) {
            const int r = p * 32 + sr;
            const int pc = (sc ^ (r & 7)) * 16;
            const char* ga = (const char*)(A + (size_t)(row0 + r) * SA_D + k0) + pc;
            __builtin_amdgcn_global_load_lds((gmem_t*)ga,
                (lds_t*)(As + p * 4096 + wave * 1024), 16, 0, 0);
            const char* gb = (const char*)(Bt + (size_t)(col0 + r) * SA_D + k0) + pc;
            __builtin_amdgcn_global_load_lds((gmem_t*)gb,
                (lds_t*)(Bs + p * 4096 + wave * 1024), 16, 0, 0);
        }
        __syncthreads();

#pragma unroll
        for (int s = 0; s < 2; ++s) {
            bf16x8 af[2], bfr[2];
#pragma unroll
            for (int mi = 0; mi < 2; ++mi) {
                const int row = wm * 32 + mi * 16 + m;
                const int pc = (s * 4 + quad) ^ (row & 7);
                af[mi] = *reinterpret_cast<const bf16x8*>(As + row * 128 + pc * 16);
            }
#pragma unroll
            for (int ni = 0; ni < 2; ++ni) {
                const int col = wn * 32 + ni * 16 + m;
                const int pc = (s * 4 + quad) ^ (col & 7);
                bfr[ni] = *reinterpret_cast<const bf16x8*>(Bs + col * 128 + pc * 16);
            }
#pragma unroll
            for (int mi = 0; mi < 2; ++mi)
#pragma unroll
                for (int ni = 0; ni < 2; ++ni)
                    acc[mi][ni] = __builtin_amdgcn_mfma_f32_16x16x32_bf16(
                        af[mi], bfr[ni], acc[mi][ni], 0, 0, 0);
        }
        __syncthreads();
    }

#pragma unroll
    for (int ni = 0; ni < 2; ++ni) {
        const int col = col0 + wn * 32 + ni * 16 + m;
        const float bv = bias[col];
#pragma unroll
        for (int mi = 0; mi < 2; ++mi) {
            const int rbase = row0 + wm * 32 + mi * 16 + quad * 4;
#pragma unroll
            for (int reg = 0; reg < 4; ++reg)
                Cout[(size_t)(rbase + reg) * SA_D + col] = acc[mi][ni][reg] + bv;
        }
    }
}

// ---------------- MFMA flash attention v8: v6 + register-prefetch staging ----------------
// Compute structure is EXACTLY R12 v6 (best measured). Staging changed from
// global_load_lds (barrier forces vmcnt(0) drain of ~32KB DMA each iter) to
// register prefetch: load tile kt+1 into 16 VGPRs/lane (plain dwordx4, same
// swizzled global addresses) right after the write-barrier, compute tile kt,
// then ds_write_b128 regs->LDS at the next iteration top. Barriers now wait
// only on LDS writes; global latency is hidden behind the whole compute phase.
// LDS layout and compute identical to v6 (writes go to base+lane*16, the same
// physical placement the DMA produced).
__global__ __launch_bounds__(512, 4) void flash_mfma_kernel(
    const __hip_bfloat16* __restrict__ Qb,  // [N][D], pre-scaled by SC2
    const __hip_bfloat16* __restrict__ Kb,  // [N][D]
    const __hip_bfloat16* __restrict__ Vt,  // [D][N], keys permuted per 64-block
    __hip_bfloat16* __restrict__ O)         // [N][D]
{
    const int b = blockIdx.x;
    const int h = b & 15;
    const int qraw = b >> 4;
    const int qt = (qraw < 16) ? qraw : 47 - qraw;  // fold for CU balance
    const int row0 = qt * 64;
    const int ntiles = (qt >> 1) + 1;               // 128-key tiles

    const int tid = threadIdx.x;
    const int wave = tid >> 6, lane = tid & 63;
    const int g = wave >> 2, w4 = wave & 3;         // group, wave-in-group
    const int ln = lane & 15, quad = lane >> 4;

    __shared__ __align__(16) char Qs[64 * 128];     // [qrow][dim] bf16
    __shared__ __align__(16) char Ks[128 * 128];    // [key][dim] bf16 (reused as merge buf)
    __shared__ __align__(16) char Vs[64 * 256];     // [dim][key'] bf16, 128 keys/row
    __shared__ __align__(16) char Ps[2][64 * 144];  // per-group [qrow][key'] bf16
    __shared__ float lmerge[64];

    // stage Q tile once (DMA; drained by first barrier)
    {
        const int r = wave * 8 + (lane >> 3);
        const int pc = ((lane & 7) ^ (r & 7)) * 16;
        const char* gq = (const char*)(Qb + (size_t)(row0 + r) * SA_D + h * SA_HD) + pc;
        __builtin_amdgcn_global_load_lds((gmem_t*)gq,
            (lds_t*)(Qs + wave * 1024), 16, 0, 0);
    }

    // K/V register prefetch (same swizzled addresses the v6 DMA used)
    const int kr0 = wave * 8 + (lane >> 3);           // K row within 64-row round
    const int kpc = ((lane & 7) ^ (kr0 & 7)) * 16;
    const int vr0 = wave * 4 + (lane >> 4);           // V row within 32-row round
    const int vpc = ((lane & 15) ^ (vr0 & 15)) * 16;
    bf16x8 kreg[2], vreg[2];

    auto prefetch = [&](int kt) {
#pragma unroll
        for (int p = 0; p < 2; ++p) {
            kreg[p] = *reinterpret_cast<const bf16x8*>(
                (const char*)(Kb + (size_t)(kt * 128 + p * 64 + kr0) * SA_D + h * SA_HD) + kpc);
            vreg[p] = *reinterpret_cast<const bf16x8*>(
                (const char*)(Vt + (size_t)(h * SA_HD + p * 32 + vr0) * SA_N + kt * 128) + vpc);
        }
    };
    prefetch(0);

    f32x4 oacc[4], lacc;
#pragma unroll
    for (int dg = 0; dg < 4; ++dg) oacc[dg] = (f32x4){0.f, 0.f, 0.f, 0.f};
    lacc = (f32x4){0.f, 0.f, 0.f, 0.f};

    const short one_bf = (short)0x3F80;
    const bf16x8 ones = {one_bf, one_bf, one_bf, one_bf, one_bf, one_bf, one_bf, one_bf};

    for (int kt = 0; kt < ntiles; ++kt) {
        __syncthreads();   // all waves done reading Ks/Vs (prev iter); Qs DMA drained (kt=0)
        // write prefetched tile into LDS (identical physical layout to v6 DMA)
#pragma unroll
        for (int p = 0; p < 2; ++p) {
            *reinterpret_cast<bf16x8*>(Ks + p * 8192 + wave * 1024 + lane * 16) = kreg[p];
            *reinterpret_cast<bf16x8*>(Vs + p * 8192 + wave * 1024 + lane * 16) = vreg[p];
        }
        __syncthreads();   // writes visible
        if (kt + 1 < ntiles) prefetch(kt + 1);   // lands during compute below

        // S = Q K^T : wave's 16 q-rows x group's 64 keys
        f32x4 sacc[4];
#pragma unroll
        for (int gg = 0; gg < 4; ++gg) sacc[gg] = (f32x4){0.f, 0.f, 0.f, 0.f};
        const int mrow = w4 * 16 + ln;
#pragma unroll
        for (int s = 0; s < 2; ++s) {
            const int pca = (s * 4 + quad) ^ (mrow & 7);
            bf16x8 af = *reinterpret_cast<const bf16x8*>(Qs + mrow * 128 + pca * 16);
#pragma unroll
            for (int gg = 0; gg < 4; ++gg) {
                const int krow = g * 64 + gg * 16 + ln;
                const int pcb = (s * 4 + quad) ^ (krow & 7);
                bf16x8 bf = *reinterpret_cast<const bf16x8*>(Ks + krow * 128 + pcb * 16);
                sacc[gg] = __builtin_amdgcn_mfma_f32_16x16x32_bf16(af, bf, sacc[gg], 0, 0, 0);
            }
        }

        // P = exp2(S) + causal mask; packed b64 store per row (permuted keys)
        const bool last = (kt == ntiles - 1);
        const int prow_b = w4 * 16 + quad * 4;
        const int qrow_b = row0 + prow_b;
        char* Pg = Ps[g];
#pragma unroll
        for (int reg = 0; reg < 4; ++reg) {
            union { __hip_bfloat16 hh[4]; short4 s4; } u;
#pragma unroll
            for (int gg = 0; gg < 4; ++gg) {
                const int key = kt * 128 + g * 64 + gg * 16 + ln;
                float p = exp2f(sacc[gg][reg]);
                if (last && key > (qrow_b + reg)) p = 0.f;
                u.hh[gg] = __float2bfloat16(p);
            }
            *reinterpret_cast<short4*>(Pg + (prow_b + reg) * 144 + ln * 8) = u.s4;
        }

        // O += P V ; l += P . ones   (k' order consistent between P and Vs)
#pragma unroll
        for (int s2 = 0; s2 < 2; ++s2) {
            bf16x8 pf = *reinterpret_cast<const bf16x8*>(
                Pg + (w4 * 16 + ln) * 144 + s2 * 64 + quad * 16);
            lacc = __builtin_amdgcn_mfma_f32_16x16x32_bf16(pf, ones, lacc, 0, 0, 0);
#pragma unroll
            for (int dg = 0; dg < 4; ++dg) {
                const int vrow = dg * 16 + ln;
                const int kc = g * 8 + s2 * 4 + quad;
                const int pcb = (kc ^ (vrow & 15)) * 16;
                bf16x8 vf = *reinterpret_cast<const bf16x8*>(Vs + vrow * 256 + pcb);
                oacc[dg] = __builtin_amdgcn_mfma_f32_16x16x32_bf16(pf, vf, oacc[dg], 0, 0, 0);
            }
        }
    }

    // merge groups: group 1 dumps fp32 partials into Ks (16 KB = 64x64 f32)
    __syncthreads();
    float* Kf = reinterpret_cast<float*>(Ks);
    if (g == 1) {
#pragma unroll
        for (int reg = 0; reg < 4; ++reg) {
            const int row = w4 * 16 + quad * 4 + reg;
#pragma unroll
            for (int dg = 0; dg < 4; ++dg)
                Kf[row * 64 + dg * 16 + ln] = oacc[dg][reg];
            if (ln == 0) lmerge[row] = lacc[reg];
        }
    }
    __syncthreads();
    if (g == 0) {
#pragma unroll
        for (int reg = 0; reg < 4; ++reg) {
            const int row = w4 * 16 + quad * 4 + reg;
            const float inv = 1.0f / (lacc[reg] + lmerge[row]);
            const int qrow = row0 + row;
#pragma unroll
            for (int dg = 0; dg < 4; ++dg)
                O[(size_t)qrow * SA_D + h * SA_HD + dg * 16 + ln] =
                    __float2bfloat16((oacc[dg][reg] + Kf[row * 64 + dg * 16 + ln]) * inv);
        }
    }
}

extern "C" void kernel_launch(void* const* d_in, const int* in_sizes, int n_in,
                              void* d_out, int out_size, void* d_ws, size_t ws_size,
                              hipStream_t stream) {
    const float* x  = (const float*)d_in[0];
    const float* Wq = (const float*)d_in[1];
    const float* bq = (const float*)d_in[2];
    const float* Wk = (const float*)d_in[3];
    const float* bk = (const float*)d_in[4];
    const float* Wv = (const float*)d_in[5];
    const float* bv = (const float*)d_in[6];
    const float* Wo = (const float*)d_in[7];
    const float* bo = (const float*)d_in[8];
    float* out = (float*)d_out;

    const size_t ND = (size_t)SA_N * SA_D;
    const size_t DD = (size_t)SA_D * SA_D;
    __hip_bfloat16* xbf   = (__hip_bfloat16*)d_ws;
    __hip_bfloat16* WtAll = xbf + ND;
    __hip_bfloat16* Qb    = WtAll + 4 * DD;
    __hip_bfloat16* Kb    = Qb + ND;
    __hip_bfloat16* VtT   = Kb + ND;
    __hip_bfloat16* Abf   = VtT + ND;

    prep_kernel<<<dim3(32, 32, 6), 256, 0, stream>>>(x, Wq, Wk, Wv, Wo, xbf, WtAll);
    gemm_qkv_kernel<<<dim3(SA_D / 32, SA_N / 64), 256, 0, stream>>>(
        xbf, WtAll, bq, bk, bv, Qb, Kb, VtT);
    flash_mfma_kernel<<<dim3(512), 512, 0, stream>>>(Qb, Kb, VtT, Abf);
    gemm_out_kernel<<<dim3(SA_D / 64, SA_N / 64), 256, 0, stream>>>(
        Abf, WtAll + 3 * DD, bo, out);
}